// Round 3
// baseline (2148.718 us; speedup 1.0000x reference)
//
#include <hip/hip_runtime.h>

#define NB 4
#define NN 16384
#define NPT 1024
#define NS 32
#define CIN 64
#define C0 67

typedef float v2f __attribute__((ext_vector_type(2)));

// DPP wave64 reduce ladders (VALU-only; invalid source lanes keep 'old' => idempotent-safe for min/max)
#define DPP_MAXF(r, ctrl)                                                                   \
  {                                                                                         \
    unsigned _m = (unsigned)__builtin_amdgcn_update_dpp(                                    \
        (int)__float_as_uint(r), (int)__float_as_uint(r), ctrl, 0xf, 0xf, false);           \
    r = fmaxf(r, __uint_as_float(_m));                                                      \
  }
#define DPP_MINU(r, ctrl)                                                                   \
  {                                                                                         \
    unsigned _m = (unsigned)__builtin_amdgcn_update_dpp((int)(r), (int)(r), ctrl, 0xf, 0xf, \
                                                        false);                             \
    r = (r < _m) ? r : _m;                                                                  \
  }

// ---------------- FPS: one block per batch, 512 threads, 32 pts/thread ----------------
// Rounds 0-2 evidence: all data layouts (regs@256-budget, regs@128-budget, LDS-scalar) land
// at ~2900-3200 cyc of VALU ISSUE per SIMD per iteration (VALUBusy~73% x dur) vs 1536 ideal
// -> the kernel is VALU-issue-bound and the compiler emits ~2x the source op count.
// Fix: cut real ops with packed fp32 (CDNA2+ v_pk_add/mul_f32, full rate, IEEE RN per half):
//   - sub via pre-negated centroid: x + (-c) == x - c bit-exactly
//   - 8 pk ops per POINT-PAIR + 2 v_min + 1 v_max3 => ~5.5 ops/pt (was ~12+overhead)
//   - argmax index moved OUT of the loop: post-scan md[k]==bv (fmax returns an operand
//     exactly => bitwise-safe equality), descending k keeps smallest index
// x,y in LDS [tid][k] stride-34 pad (ds_read_b64 pairs; each bank hit exactly 4x/wave =
// conflict-free minimum); z pairs + md in regs (~110 live < 256 budget @ waves_per_eu(2,2)).
// Tail: DPP two-phase wave reduce (f32-max ladder then u32-min over tied indices) replaces
// the ds-shuffle u64 butterfly; centroid x,y re-read from LDS broadcast. Tie-break semantics
// (smallest global j) preserved: within-thread smallest k, cross-wave u64 key with ~j.
extern "C" __global__ __attribute__((amdgpu_waves_per_eu(2, 2))) __launch_bounds__(512)
void fps_kernel(const float* __restrict__ xyz, float* __restrict__ newxyz) {
  const int b = blockIdx.x;
  const int tid = threadIdx.x;          // 0..511
  const int wv = tid >> 6, lane = tid & 63;
  const float* base = xyz + (size_t)b * (NN * 3);
  __shared__ __align__(16) float sxp[512 * 34];  // 69632 B, row stride 34 floats (2 pad)
  __shared__ __align__(16) float syp[512 * 34];  // 69632 B
  __shared__ unsigned long long part[2][8];      // parity-double-buffered wave winners
  float* rowx = sxp + tid * 34;
  float* rowy = syp + tid * 34;
  v2f z2[16];
  float md[32];
#pragma unroll
  for (int k = 0; k < 32; ++k) {
    int j = (k << 9) + tid;            // global index mapping (identical to prior rounds)
    rowx[k] = base[3 * j + 0];
    rowy[k] = base[3 * j + 1];
    z2[k >> 1][k & 1] = base[3 * j + 2];
    md[k] = 1e10f;
  }
  float* onew = newxyz + (size_t)b * (NPT * 3);
  // iteration 0: centroid = point 0 (broadcast load)
  float cx = base[0], cy = base[1], cz = base[2];
  if (tid == 0) { onew[0] = cx; onew[1] = cy; onew[2] = cz; }
  v2f ncx2 = {-cx, -cx}, ncy2 = {-cy, -cy}, ncz2 = {-cz, -cz};
  __syncthreads();
  for (int it = 1; it < NPT; ++it) {
    const int p = it & 1;
    float bv = -1.0f;
#pragma unroll
    for (int q = 0; q < 16; ++q) {
      v2f xv = *(const v2f*)(rowx + 2 * q);     // ds_read_b64, 8B-aligned (136*tid+8q)
      v2f yv = *(const v2f*)(rowy + 2 * q);
      v2f dx, dy, dz, qx, qy, qz, ss, dd;
      // x + (-c) == x - c exactly; each pk half is scalar IEEE RN => bit-exact vs ref
      asm("v_pk_add_f32 %0, %1, %2" : "=v"(dx) : "v"(xv), "v"(ncx2));
      asm("v_pk_add_f32 %0, %1, %2" : "=v"(dy) : "v"(yv), "v"(ncy2));
      asm("v_pk_add_f32 %0, %1, %2" : "=v"(dz) : "v"(z2[q]), "v"(ncz2));
      asm("v_pk_mul_f32 %0, %1, %2" : "=v"(qx) : "v"(dx), "v"(dx));
      asm("v_pk_mul_f32 %0, %1, %2" : "=v"(qy) : "v"(dy), "v"(dy));
      asm("v_pk_mul_f32 %0, %1, %2" : "=v"(qz) : "v"(dz), "v"(dz));
      asm("v_pk_add_f32 %0, %1, %2" : "=v"(ss) : "v"(qx), "v"(qy));   // dx2+dy2
      asm("v_pk_add_f32 %0, %1, %2" : "=v"(dd) : "v"(ss), "v"(qz));   // +dz2
      md[2 * q] = fminf(md[2 * q], dd.x);
      md[2 * q + 1] = fminf(md[2 * q + 1], dd.y);
      bv = fmaxf(bv, fmaxf(md[2 * q], md[2 * q + 1]));   // fuses to v_max3_f32
    }
    // post-scan: smallest k with md[k]==bv (descending overwrite keeps smallest)
    int bk = 0;
#pragma unroll
    for (int k = 31; k >= 0; --k) bk = (md[k] == bv) ? k : bk;
    int bestj = (bk << 9) + tid;
    // phase A: wave max of bv via DPP ladder -> lane 63
    float r = bv;
    DPP_MAXF(r, 0x111); DPP_MAXF(r, 0x112); DPP_MAXF(r, 0x114);
    DPP_MAXF(r, 0x118); DPP_MAXF(r, 0x142); DPP_MAXF(r, 0x143);
    float wmax = __uint_as_float((unsigned)__builtin_amdgcn_readlane((int)__float_as_uint(r), 63));
    // phase B: min index among lanes holding the max (exact equality: fmax returns operands)
    unsigned cj = (bv == wmax) ? (unsigned)bestj : 0x7FFFFFFFu;
    DPP_MINU(cj, 0x111); DPP_MINU(cj, 0x112); DPP_MINU(cj, 0x114);
    DPP_MINU(cj, 0x118); DPP_MINU(cj, 0x142); DPP_MINU(cj, 0x143);
    unsigned jw = (unsigned)__builtin_amdgcn_readlane((int)cj, 63);
    if (lane == 0)
      part[p][wv] = ((unsigned long long)__float_as_uint(wmax) << 32) | (unsigned)(~jw);
    __syncthreads();
    // every thread merges the 8 wave winners (broadcast LDS reads); ~j orders ties to min j
    unsigned long long g = part[p][0];
#pragma unroll
    for (int w = 1; w < 8; ++w) {
      unsigned long long o = part[p][w];
      g = (o > g) ? o : g;
    }
    int j = (int)(~(unsigned)g);
    int js = __builtin_amdgcn_readfirstlane(j);
    int rr = js & 511, kk = js >> 9;
    cx = sxp[rr * 34 + kk];            // LDS broadcast, bit-identical to stored coords
    cy = syp[rr * 34 + kk];
    cz = base[3 * js + 2];             // uniform global load (z not staged)
    if (tid == 0) { float* o3 = onew + 3 * it; o3[0] = cx; o3[1] = cy; o3[2] = cz; }
    ncx2.x = -cx; ncx2.y = -cx;
    ncy2.x = -cy; ncy2.y = -cy;
    ncz2.x = -cz; ncz2.y = -cz;
    // no second barrier: next iteration writes the OTHER parity's part[] cells
  }
}

// ---------------- Ball query: one wave per centroid, ordered append with early exit ----------------
extern "C" __global__ __launch_bounds__(256)
void ball_kernel(const float* __restrict__ xyz, const float* __restrict__ newxyz,
                 int* __restrict__ ballidx) {
  const int lwv = threadIdx.x >> 6, lane = threadIdx.x & 63;
  const int wid = blockIdx.x * 4 + lwv;  // centroid id, 0..4095
  const int b = wid >> 10;
  const float* base = xyz + (size_t)b * (NN * 3);
  const float* c = newxyz + (size_t)wid * 3;
  float cx = c[0], cy = c[1], cz = c[2];
  float c2 = __fadd_rn(__fadd_rn(__fmul_rn(cx, cx), __fmul_rn(cy, cy)), __fmul_rn(cz, cz));
  __shared__ int list[4][NS];
  int cnt = 0;
  for (int j0 = 0; j0 < NN; j0 += 64) {
    int j = j0 + lane;
    float xx = base[3 * j + 0], xy = base[3 * j + 1], xz = base[3 * j + 2];
    float x2 = __fadd_rn(__fadd_rn(__fmul_rn(xx, xx), __fmul_rn(xy, xy)), __fmul_rn(xz, xz));
    float dt = __fadd_rn(__fadd_rn(__fmul_rn(cx, xx), __fmul_rn(cy, xy)), __fmul_rn(cz, xz));
    float d2 = __fsub_rn(__fadd_rn(c2, x2), __fmul_rn(2.0f, dt));  // (c2+x2) - 2*dot
    bool in = d2 < 0.25f;
    unsigned long long msk = __ballot(in);
    if (in) {
      int pos = cnt + (int)__popcll(msk & ((1ull << lane) - 1ull));
      if (pos < NS) list[lwv][pos] = j;
    }
    cnt += (int)__popcll(msk);
    if (cnt >= NS) break;
  }
  if (lane < NS) {
    int v;
    if (cnt == 0) v = 0;
    else v = (lane < cnt) ? list[lwv][lane] : list[lwv][0];
    ballidx[wid * NS + lane] = v;
  }
}

// ---------------- Gather + MLP(67->64->64->128) + max-pool, one block per (b,m) ----------------
extern "C" __global__ __launch_bounds__(256)
void mlp_kernel(const float* __restrict__ xyz, const float* __restrict__ feats,
                const float* __restrict__ newxyz, const int* __restrict__ ballidx,
                const float* __restrict__ W1, const float* __restrict__ b1,
                const float* __restrict__ W2, const float* __restrict__ b2,
                const float* __restrict__ W3, const float* __restrict__ b3,
                float* __restrict__ outf) {
  const int bm = blockIdx.x;
  const int b = bm >> 10, m = bm & 1023;
  const int tid = threadIdx.x;
  __align__(16) __shared__ float bufA[32 * 68];  // h0 (stride 68), then h2 (stride 64)
  __align__(16) __shared__ float bufB[32 * 64];  // h1, then partial max
  __shared__ int sidx[NS];
  if (tid < NS) sidx[tid] = ballidx[bm * NS + tid];
  const float* cb = newxyz + (size_t)bm * 3;
  float cx = cb[0], cy = cb[1], cz = cb[2];
  __syncthreads();
  // gather: 8 threads per sample
  {
    int s = tid >> 3, q = tid & 7;
    int j = sidx[s];
    float* row = bufA + s * 68;
    const float* fb = feats + (size_t)b * (CIN * NN) + j;
#pragma unroll
    for (int u = 0; u < 8; ++u) {
      int cc = (q << 3) + u;
      row[3 + cc] = fb[(size_t)cc * NN];
    }
    if (q == 0) {
      const float* p = xyz + ((size_t)b * NN + j) * 3;
      row[0] = __fsub_rn(p[0], cx);
      row[1] = __fsub_rn(p[1], cy);
      row[2] = __fsub_rn(p[2], cz);
      row[67] = 0.0f;
    }
  }
  __syncthreads();
  // layer 1: 67->64   (thread = (o, 8-sample group))
  {
    const int o = tid & 63, g = tid >> 6;
    float w[68];
    const float* wr = W1 + o * C0;
#pragma unroll
    for (int c = 0; c < C0; ++c) w[c] = wr[c];
    w[67] = 0.0f;
    float bias = b1[o];
    float acc[8];
#pragma unroll
    for (int k = 0; k < 8; ++k) acc[k] = bias;
#pragma unroll
    for (int c = 0; c < 68; c += 4) {
#pragma unroll
      for (int k = 0; k < 8; ++k) {
        float4 h = *(const float4*)(bufA + (g * 8 + k) * 68 + c);
        acc[k] = fmaf(w[c], h.x, acc[k]);
        acc[k] = fmaf(w[c + 1], h.y, acc[k]);
        acc[k] = fmaf(w[c + 2], h.z, acc[k]);
        acc[k] = fmaf(w[c + 3], h.w, acc[k]);
      }
    }
#pragma unroll
    for (int k = 0; k < 8; ++k) bufB[(g * 8 + k) * 64 + o] = fmaxf(acc[k], 0.0f);
  }
  __syncthreads();
  // layer 2: 64->64, h2 into bufA with stride 64
  {
    const int o = tid & 63, g = tid >> 6;
    float w[64];
    const float* wr = W2 + o * 64;
#pragma unroll
    for (int c = 0; c < 64; ++c) w[c] = wr[c];
    float bias = b2[o];
    float acc[8];
#pragma unroll
    for (int k = 0; k < 8; ++k) acc[k] = bias;
#pragma unroll
    for (int c = 0; c < 64; c += 4) {
#pragma unroll
      for (int k = 0; k < 8; ++k) {
        float4 h = *(const float4*)(bufB + (g * 8 + k) * 64 + c);
        acc[k] = fmaf(w[c], h.x, acc[k]);
        acc[k] = fmaf(w[c + 1], h.y, acc[k]);
        acc[k] = fmaf(w[c + 2], h.z, acc[k]);
        acc[k] = fmaf(w[c + 3], h.w, acc[k]);
      }
    }
#pragma unroll
    for (int k = 0; k < 8; ++k) bufA[(g * 8 + k) * 64 + o] = fmaxf(acc[k], 0.0f);
  }
  __syncthreads();
  // layer 3: 64->128 (thread = (o128, 16-sample group)), fused relu+max
  {
    const int o = tid & 127, g = tid >> 7;
    float w[64];
    const float* wr = W3 + o * 64;
#pragma unroll
    for (int c = 0; c < 64; ++c) w[c] = wr[c];
    float bias = b3[o];
    float acc[16];
#pragma unroll
    for (int k = 0; k < 16; ++k) acc[k] = bias;
#pragma unroll
    for (int kb = 0; kb < 16; kb += 8) {   // 8-sample sub-blocks to limit live registers
#pragma unroll
      for (int c = 0; c < 64; c += 4) {
#pragma unroll
        for (int k = 0; k < 8; ++k) {
          float4 h = *(const float4*)(bufA + (g * 16 + kb + k) * 64 + c);
          acc[kb + k] = fmaf(w[c], h.x, acc[kb + k]);
          acc[kb + k] = fmaf(w[c + 1], h.y, acc[kb + k]);
          acc[kb + k] = fmaf(w[c + 2], h.z, acc[kb + k]);
          acc[kb + k] = fmaf(w[c + 3], h.w, acc[kb + k]);
        }
      }
    }
    float mx = 0.0f;
#pragma unroll
    for (int k = 0; k < 16; ++k) mx = fmaxf(mx, fmaxf(acc[k], 0.0f));
    bufB[g * 128 + o] = mx;
  }
  __syncthreads();
  if (tid < 128) {
    float v = fmaxf(bufB[tid], bufB[128 + tid]);
    outf[((size_t)b * 128 + tid) * NPT + m] = v;
  }
}

extern "C" void kernel_launch(void* const* d_in, const int* in_sizes, int n_in,
                              void* d_out, int out_size, void* d_ws, size_t ws_size,
                              hipStream_t stream) {
  const float* xyz   = (const float*)d_in[0];
  const float* feats = (const float*)d_in[1];
  const float* W1 = (const float*)d_in[2];
  const float* b1 = (const float*)d_in[3];
  const float* W2 = (const float*)d_in[4];
  const float* b2 = (const float*)d_in[5];
  const float* W3 = (const float*)d_in[6];
  const float* b3 = (const float*)d_in[7];
  float* out = (float*)d_out;
  float* newxyz = out;                 // (4,1024,3)
  float* outf = out + NB * NPT * 3;    // (4,128,1024)
  int* ballidx = (int*)d_ws;           // 4096*32 ints

  hipLaunchKernelGGL(fps_kernel, dim3(NB), dim3(512), 0, stream, xyz, newxyz);
  hipLaunchKernelGGL(ball_kernel, dim3(NB * NPT / 4), dim3(256), 0, stream, xyz, newxyz, ballidx);
  hipLaunchKernelGGL(mlp_kernel, dim3(NB * NPT), dim3(256), 0, stream,
                     xyz, feats, newxyz, ballidx, W1, b1, W2, b2, W3, b3, outf);
}

// Round 5
// 1829.973 us; speedup vs baseline: 1.1742x; 1.1742x over previous
//
#include <hip/hip_runtime.h>

#define NB 4
#define NN 16384
#define NPT 1024
#define NS 32
#define CIN 64
#define C0 67

typedef float v2f __attribute__((ext_vector_type(2)));

// DPP wave64 reduce ladders (VALU-only; HW-verified correct in round 3's passing run)
#define DPP_MAXF(r, ctrl)                                                                   \
  {                                                                                         \
    unsigned _m = (unsigned)__builtin_amdgcn_update_dpp(                                    \
        (int)__float_as_uint(r), (int)__float_as_uint(r), ctrl, 0xf, 0xf, false);           \
    r = fmaxf(r, __uint_as_float(_m));                                                      \
  }
#define DPP_MINU(r, ctrl)                                                                   \
  {                                                                                         \
    unsigned _m = (unsigned)__builtin_amdgcn_update_dpp((int)(r), (int)(r), ctrl, 0xf, 0xf, \
                                                        false);                             \
    r = (r < _m) ? r : _m;                                                                  \
  }

// ---------------- FPS: one block per batch, 512 threads, 32 pts/thread ----------------
// Round-4 postmortem killed the "codegen bloat" theory: round 0 already issues ~11 VALU
// instr/pt (ideal scalar) -- AGPR-parked data is read directly by VALU (legal gfx90a+),
// so rounds 1-3's layout churn was chasing nothing. The only 2x lever on this 72%-VALU
// loop is packed FP32. This round = round-0 structure + the scan in float2 (compiler
// selects v_pk_add/mul_f32; NO inline asm) + round-3's HW-verified post-scan/DPP tail.
//   - #pragma clang fp contract(off): forbids FMA fusion (HIP default fast-honor-pragmas)
//     -> each pk half is scalar IEEE RN in the reference's exact order => bit-exact.
//   - x-c as vector sub (exact per half); (dx2+dy2)+dz2 order preserved.
//   - argmax: post-scan md[k]==bv (v_min/v_max return operands bitwise => equality exact),
//     descending k keeps smallest k; DPP wave-max then min-index; u64 key ~j cross-wave
//     => global smallest-index tie-break, matching numpy argmax. (All round-3-verified.)
extern "C" __global__ __attribute__((amdgpu_waves_per_eu(2, 2))) __launch_bounds__(512)
void fps_kernel(const float* __restrict__ xyz, float* __restrict__ newxyz) {
  const int b = blockIdx.x;
  const int tid = threadIdx.x;          // 0..511
  const int wv = tid >> 6, lane = tid & 63;
  const float* base = xyz + (size_t)b * (NN * 3);
  __shared__ unsigned long long part[2][8];  // parity-double-buffered wave-winner keys
  v2f x2[16], y2[16], z2[16], m2[16];
#pragma unroll
  for (int k = 0; k < 32; ++k) {
    int j = (k << 9) + tid;            // same global index mapping as rounds 0-3
    x2[k >> 1][k & 1] = base[3 * j + 0];
    y2[k >> 1][k & 1] = base[3 * j + 1];
    z2[k >> 1][k & 1] = base[3 * j + 2];
    m2[k >> 1][k & 1] = 1e10f;
  }
  float* onew = newxyz + (size_t)b * (NPT * 3);
  // iteration 0: centroid = point 0 (broadcast load)
  float cx = base[0], cy = base[1], cz = base[2];
  if (tid == 0) { onew[0] = cx; onew[1] = cy; onew[2] = cz; }
  v2f cx2 = {cx, cx}, cy2 = {cy, cy}, cz2 = {cz, cz};
  for (int it = 1; it < NPT; ++it) {
    const int p = it & 1;
    float bv = -1.0f;
    {
#pragma clang fp contract(off)
#pragma unroll
      for (int q = 0; q < 16; ++q) {
        v2f dx = x2[q] - cx2;          // v_pk_add_f32 (neg) : exact IEEE sub per half
        v2f dy = y2[q] - cy2;
        v2f dz = z2[q] - cz2;
        v2f qx = dx * dx;              // v_pk_mul_f32, no contraction (pragma)
        v2f qy = dy * dy;
        v2f qz = dz * dz;
        v2f ss = qx + qy;              // (dx2+dy2)
        v2f dd = ss + qz;              // +dz2   -- reference's exact order
        float a = fminf(m2[q].x, dd.x);
        float bmn = fminf(m2[q].y, dd.y);
        m2[q].x = a;
        m2[q].y = bmn;
        bv = fmaxf(bv, fmaxf(a, bmn)); // fuses to v_max3_f32
      }
    }
    // post-scan: smallest k with md[k]==bv (descending overwrite keeps smallest)
    int bk = 0;
#pragma unroll
    for (int k = 31; k >= 0; --k) {
      float v = (k & 1) ? m2[k >> 1].y : m2[k >> 1].x;
      bk = (v == bv) ? k : bk;
    }
    int bestj = (bk << 9) + tid;
    // phase A: wave max of bv via DPP ladder -> lane 63
    float r = bv;
    DPP_MAXF(r, 0x111); DPP_MAXF(r, 0x112); DPP_MAXF(r, 0x114);
    DPP_MAXF(r, 0x118); DPP_MAXF(r, 0x142); DPP_MAXF(r, 0x143);
    float wmax = __uint_as_float((unsigned)__builtin_amdgcn_readlane((int)__float_as_uint(r), 63));
    // phase B: min index among lanes holding the max (exact equality: min/max return operands)
    unsigned cj = (bv == wmax) ? (unsigned)bestj : 0x7FFFFFFFu;
    DPP_MINU(cj, 0x111); DPP_MINU(cj, 0x112); DPP_MINU(cj, 0x114);
    DPP_MINU(cj, 0x118); DPP_MINU(cj, 0x142); DPP_MINU(cj, 0x143);
    unsigned jw = (unsigned)__builtin_amdgcn_readlane((int)cj, 63);
    if (lane == 0)
      part[p][wv] = ((unsigned long long)__float_as_uint(wmax) << 32) | (unsigned)(~jw);
    __syncthreads();
    // every thread merges the 8 wave winners (broadcast LDS reads); ~j orders ties to min j
    unsigned long long g = part[p][0];
#pragma unroll
    for (int w = 1; w < 8; ++w) {
      unsigned long long o = part[p][w];
      g = (o > g) ? o : g;
    }
    int j = (int)(~(unsigned)g);
    int js = __builtin_amdgcn_readfirstlane(j);      // uniform -> scalar loads
    const float* pc = base + 3 * js;
    cx = pc[0]; cy = pc[1]; cz = pc[2];              // bit-identical to source coords
    if (tid == 0) { float* o3 = onew + 3 * it; o3[0] = cx; o3[1] = cy; o3[2] = cz; }
    cx2.x = cx; cx2.y = cx;
    cy2.x = cy; cy2.y = cy;
    cz2.x = cz; cz2.y = cz;
    // no second barrier: next iteration writes the OTHER parity's part[] cells
  }
}

// ---------------- Ball query: one wave per centroid, ordered append with early exit ----------------
extern "C" __global__ __launch_bounds__(256)
void ball_kernel(const float* __restrict__ xyz, const float* __restrict__ newxyz,
                 int* __restrict__ ballidx) {
  const int lwv = threadIdx.x >> 6, lane = threadIdx.x & 63;
  const int wid = blockIdx.x * 4 + lwv;  // centroid id, 0..4095
  const int b = wid >> 10;
  const float* base = xyz + (size_t)b * (NN * 3);
  const float* c = newxyz + (size_t)wid * 3;
  float cx = c[0], cy = c[1], cz = c[2];
  float c2 = __fadd_rn(__fadd_rn(__fmul_rn(cx, cx), __fmul_rn(cy, cy)), __fmul_rn(cz, cz));
  __shared__ int list[4][NS];
  int cnt = 0;
  for (int j0 = 0; j0 < NN; j0 += 64) {
    int j = j0 + lane;
    float xx = base[3 * j + 0], xy = base[3 * j + 1], xz = base[3 * j + 2];
    float x2 = __fadd_rn(__fadd_rn(__fmul_rn(xx, xx), __fmul_rn(xy, xy)), __fmul_rn(xz, xz));
    float dt = __fadd_rn(__fadd_rn(__fmul_rn(cx, xx), __fmul_rn(cy, xy)), __fmul_rn(cz, xz));
    float d2 = __fsub_rn(__fadd_rn(c2, x2), __fmul_rn(2.0f, dt));  // (c2+x2) - 2*dot
    bool in = d2 < 0.25f;
    unsigned long long msk = __ballot(in);
    if (in) {
      int pos = cnt + (int)__popcll(msk & ((1ull << lane) - 1ull));
      if (pos < NS) list[lwv][pos] = j;
    }
    cnt += (int)__popcll(msk);
    if (cnt >= NS) break;
  }
  if (lane < NS) {
    int v;
    if (cnt == 0) v = 0;
    else v = (lane < cnt) ? list[lwv][lane] : list[lwv][0];
    ballidx[wid * NS + lane] = v;
  }
}

// ---------------- Gather + MLP(67->64->64->128) + max-pool, one block per (b,m) ----------------
extern "C" __global__ __launch_bounds__(256)
void mlp_kernel(const float* __restrict__ xyz, const float* __restrict__ feats,
                const float* __restrict__ newxyz, const int* __restrict__ ballidx,
                const float* __restrict__ W1, const float* __restrict__ b1,
                const float* __restrict__ W2, const float* __restrict__ b2,
                const float* __restrict__ W3, const float* __restrict__ b3,
                float* __restrict__ outf) {
  const int bm = blockIdx.x;
  const int b = bm >> 10, m = bm & 1023;
  const int tid = threadIdx.x;
  __align__(16) __shared__ float bufA[32 * 68];  // h0 (stride 68), then h2 (stride 64)
  __align__(16) __shared__ float bufB[32 * 64];  // h1, then partial max
  __shared__ int sidx[NS];
  if (tid < NS) sidx[tid] = ballidx[bm * NS + tid];
  const float* cb = newxyz + (size_t)bm * 3;
  float cx = cb[0], cy = cb[1], cz = cb[2];
  __syncthreads();
  // gather: 8 threads per sample
  {
    int s = tid >> 3, q = tid & 7;
    int j = sidx[s];
    float* row = bufA + s * 68;
    const float* fb = feats + (size_t)b * (CIN * NN) + j;
#pragma unroll
    for (int u = 0; u < 8; ++u) {
      int cc = (q << 3) + u;
      row[3 + cc] = fb[(size_t)cc * NN];
    }
    if (q == 0) {
      const float* p = xyz + ((size_t)b * NN + j) * 3;
      row[0] = __fsub_rn(p[0], cx);
      row[1] = __fsub_rn(p[1], cy);
      row[2] = __fsub_rn(p[2], cz);
      row[67] = 0.0f;
    }
  }
  __syncthreads();
  // layer 1: 67->64   (thread = (o, 8-sample group))
  {
    const int o = tid & 63, g = tid >> 6;
    float w[68];
    const float* wr = W1 + o * C0;
#pragma unroll
    for (int c = 0; c < C0; ++c) w[c] = wr[c];
    w[67] = 0.0f;
    float bias = b1[o];
    float acc[8];
#pragma unroll
    for (int k = 0; k < 8; ++k) acc[k] = bias;
#pragma unroll
    for (int c = 0; c < 68; c += 4) {
#pragma unroll
      for (int k = 0; k < 8; ++k) {
        float4 h = *(const float4*)(bufA + (g * 8 + k) * 68 + c);
        acc[k] = fmaf(w[c], h.x, acc[k]);
        acc[k] = fmaf(w[c + 1], h.y, acc[k]);
        acc[k] = fmaf(w[c + 2], h.z, acc[k]);
        acc[k] = fmaf(w[c + 3], h.w, acc[k]);
      }
    }
#pragma unroll
    for (int k = 0; k < 8; ++k) bufB[(g * 8 + k) * 64 + o] = fmaxf(acc[k], 0.0f);
  }
  __syncthreads();
  // layer 2: 64->64, h2 into bufA with stride 64
  {
    const int o = tid & 63, g = tid >> 6;
    float w[64];
    const float* wr = W2 + o * 64;
#pragma unroll
    for (int c = 0; c < 64; ++c) w[c] = wr[c];
    float bias = b2[o];
    float acc[8];
#pragma unroll
    for (int k = 0; k < 8; ++k) acc[k] = bias;
#pragma unroll
    for (int c = 0; c < 64; c += 4) {
#pragma unroll
      for (int k = 0; k < 8; ++k) {
        float4 h = *(const float4*)(bufB + (g * 8 + k) * 64 + c);
        acc[k] = fmaf(w[c], h.x, acc[k]);
        acc[k] = fmaf(w[c + 1], h.y, acc[k]);
        acc[k] = fmaf(w[c + 2], h.z, acc[k]);
        acc[k] = fmaf(w[c + 3], h.w, acc[k]);
      }
    }
#pragma unroll
    for (int k = 0; k < 8; ++k) bufA[(g * 8 + k) * 64 + o] = fmaxf(acc[k], 0.0f);
  }
  __syncthreads();
  // layer 3: 64->128 (thread = (o128, 16-sample group)), fused relu+max
  {
    const int o = tid & 127, g = tid >> 7;
    float w[64];
    const float* wr = W3 + o * 64;
#pragma unroll
    for (int c = 0; c < 64; ++c) w[c] = wr[c];
    float bias = b3[o];
    float acc[16];
#pragma unroll
    for (int k = 0; k < 16; ++k) acc[k] = bias;
#pragma unroll
    for (int kb = 0; kb < 16; kb += 8) {   // 8-sample sub-blocks to limit live registers
#pragma unroll
      for (int c = 0; c < 64; c += 4) {
#pragma unroll
        for (int k = 0; k < 8; ++k) {
          float4 h = *(const float4*)(bufA + (g * 16 + kb + k) * 64 + c);
          acc[kb + k] = fmaf(w[c], h.x, acc[kb + k]);
          acc[kb + k] = fmaf(w[c + 1], h.y, acc[kb + k]);
          acc[kb + k] = fmaf(w[c + 2], h.z, acc[kb + k]);
          acc[kb + k] = fmaf(w[c + 3], h.w, acc[kb + k]);
        }
      }
    }
    float mx = 0.0f;
#pragma unroll
    for (int k = 0; k < 16; ++k) mx = fmaxf(mx, fmaxf(acc[k], 0.0f));
    bufB[g * 128 + o] = mx;
  }
  __syncthreads();
  if (tid < 128) {
    float v = fmaxf(bufB[tid], bufB[128 + tid]);
    outf[((size_t)b * 128 + tid) * NPT + m] = v;
  }
}

extern "C" void kernel_launch(void* const* d_in, const int* in_sizes, int n_in,
                              void* d_out, int out_size, void* d_ws, size_t ws_size,
                              hipStream_t stream) {
  const float* xyz   = (const float*)d_in[0];
  const float* feats = (const float*)d_in[1];
  const float* W1 = (const float*)d_in[2];
  const float* b1 = (const float*)d_in[3];
  const float* W2 = (const float*)d_in[4];
  const float* b2 = (const float*)d_in[5];
  const float* W3 = (const float*)d_in[6];
  const float* b3 = (const float*)d_in[7];
  float* out = (float*)d_out;
  float* newxyz = out;                 // (4,1024,3)
  float* outf = out + NB * NPT * 3;    // (4,128,1024)
  int* ballidx = (int*)d_ws;           // 4096*32 ints

  hipLaunchKernelGGL(fps_kernel, dim3(NB), dim3(512), 0, stream, xyz, newxyz);
  hipLaunchKernelGGL(ball_kernel, dim3(NB * NPT / 4), dim3(256), 0, stream, xyz, newxyz, ballidx);
  hipLaunchKernelGGL(mlp_kernel, dim3(NB * NPT), dim3(256), 0, stream,
                     xyz, feats, newxyz, ballidx, W1, b1, W2, b2, W3, b3, outf);
}

// Round 6
// 1809.864 us; speedup vs baseline: 1.1872x; 1.0111x over previous
//
#include <hip/hip_runtime.h>

#define NB 4
#define NN 16384
#define NPT 1024
#define NS 32
#define CIN 64
#define C0 67

typedef float v2f __attribute__((ext_vector_type(2)));

// DPP wave64 reduce ladders (VALU-only; HW-verified correct in rounds 3/5 passing runs)
#define DPP_MAXF(r, ctrl)                                                                   \
  {                                                                                         \
    unsigned _m = (unsigned)__builtin_amdgcn_update_dpp(                                    \
        (int)__float_as_uint(r), (int)__float_as_uint(r), ctrl, 0xf, 0xf, false);           \
    r = fmaxf(r, __uint_as_float(_m));                                                      \
  }
#define DPP_MINU(r, ctrl)                                                                   \
  {                                                                                         \
    unsigned _m = (unsigned)__builtin_amdgcn_update_dpp((int)(r), (int)(r), ctrl, 0xf, 0xf, \
                                                        false);                             \
    r = (r < _m) ? r : _m;                                                                  \
  }

// ---------------- FPS: one block per batch, 512 threads, 32 pts/thread ----------------
// UNCHANGED from round 5 (1546 us, proven). Round-5 postmortem: v_pk_*_f32 occupies 2
// issue slots on CDNA4 (157.3 TF spec = scalar rate) => pk is slot-neutral; round 5's
// gain was the DPP tail. Loop is at the bit-exactness-constrained slot floor (~9.5/pt);
// 2-wave duty ~77%; tail conserved across all tried structures. Do not churn.
extern "C" __global__ __attribute__((amdgpu_waves_per_eu(2, 2))) __launch_bounds__(512)
void fps_kernel(const float* __restrict__ xyz, float* __restrict__ newxyz) {
  const int b = blockIdx.x;
  const int tid = threadIdx.x;          // 0..511
  const int wv = tid >> 6, lane = tid & 63;
  const float* base = xyz + (size_t)b * (NN * 3);
  __shared__ unsigned long long part[2][8];  // parity-double-buffered wave-winner keys
  v2f x2[16], y2[16], z2[16], m2[16];
#pragma unroll
  for (int k = 0; k < 32; ++k) {
    int j = (k << 9) + tid;            // same global index mapping as rounds 0-3
    x2[k >> 1][k & 1] = base[3 * j + 0];
    y2[k >> 1][k & 1] = base[3 * j + 1];
    z2[k >> 1][k & 1] = base[3 * j + 2];
    m2[k >> 1][k & 1] = 1e10f;
  }
  float* onew = newxyz + (size_t)b * (NPT * 3);
  // iteration 0: centroid = point 0 (broadcast load)
  float cx = base[0], cy = base[1], cz = base[2];
  if (tid == 0) { onew[0] = cx; onew[1] = cy; onew[2] = cz; }
  v2f cx2 = {cx, cx}, cy2 = {cy, cy}, cz2 = {cz, cz};
  for (int it = 1; it < NPT; ++it) {
    const int p = it & 1;
    float bv = -1.0f;
    {
#pragma clang fp contract(off)
#pragma unroll
      for (int q = 0; q < 16; ++q) {
        v2f dx = x2[q] - cx2;          // exact IEEE sub per half
        v2f dy = y2[q] - cy2;
        v2f dz = z2[q] - cz2;
        v2f qx = dx * dx;              // no contraction (pragma)
        v2f qy = dy * dy;
        v2f qz = dz * dz;
        v2f ss = qx + qy;              // (dx2+dy2)
        v2f dd = ss + qz;              // +dz2   -- reference's exact order
        float a = fminf(m2[q].x, dd.x);
        float bmn = fminf(m2[q].y, dd.y);
        m2[q].x = a;
        m2[q].y = bmn;
        bv = fmaxf(bv, fmaxf(a, bmn)); // fuses to v_max3_f32
      }
    }
    // post-scan: smallest k with md[k]==bv (descending overwrite keeps smallest)
    int bk = 0;
#pragma unroll
    for (int k = 31; k >= 0; --k) {
      float v = (k & 1) ? m2[k >> 1].y : m2[k >> 1].x;
      bk = (v == bv) ? k : bk;
    }
    int bestj = (bk << 9) + tid;
    // phase A: wave max of bv via DPP ladder -> lane 63
    float r = bv;
    DPP_MAXF(r, 0x111); DPP_MAXF(r, 0x112); DPP_MAXF(r, 0x114);
    DPP_MAXF(r, 0x118); DPP_MAXF(r, 0x142); DPP_MAXF(r, 0x143);
    float wmax = __uint_as_float((unsigned)__builtin_amdgcn_readlane((int)__float_as_uint(r), 63));
    // phase B: min index among lanes holding the max (exact equality: min/max return operands)
    unsigned cj = (bv == wmax) ? (unsigned)bestj : 0x7FFFFFFFu;
    DPP_MINU(cj, 0x111); DPP_MINU(cj, 0x112); DPP_MINU(cj, 0x114);
    DPP_MINU(cj, 0x118); DPP_MINU(cj, 0x142); DPP_MINU(cj, 0x143);
    unsigned jw = (unsigned)__builtin_amdgcn_readlane((int)cj, 63);
    if (lane == 0)
      part[p][wv] = ((unsigned long long)__float_as_uint(wmax) << 32) | (unsigned)(~jw);
    __syncthreads();
    // every thread merges the 8 wave winners (broadcast LDS reads); ~j orders ties to min j
    unsigned long long g = part[p][0];
#pragma unroll
    for (int w = 1; w < 8; ++w) {
      unsigned long long o = part[p][w];
      g = (o > g) ? o : g;
    }
    int j = (int)(~(unsigned)g);
    int js = __builtin_amdgcn_readfirstlane(j);      // uniform -> scalar loads
    const float* pc = base + 3 * js;
    cx = pc[0]; cy = pc[1]; cz = pc[2];              // bit-identical to source coords
    if (tid == 0) { float* o3 = onew + 3 * it; o3[0] = cx; o3[1] = cy; o3[2] = cz; }
    cx2.x = cx; cx2.y = cx;
    cy2.x = cy; cy2.y = cy;
    cz2.x = cz; cz2.y = cz;
    // no second barrier: next iteration writes the OTHER parity's part[] cells
  }
}

// ---------------- Feature transpose: (B,C,N) -> (B,N,C), 64x64 LDS tiles ----------------
// mlp's gather reads feats[cc*NN + j] at scattered j: 64 lanes x 64 distinct 64B lines,
// 4B used each => ~16x line-waste on the L2/L3 path. One 16.8MB point-major copy makes
// each sample's 64 channels one contiguous 256B read. Bit-preserving (pure copy).
extern "C" __global__ __launch_bounds__(256)
void tr_kernel(const float* __restrict__ feats, float* __restrict__ featsT) {
  const int tile = blockIdx.x & 255;    // NN/64 = 256 tiles
  const int b = blockIdx.x >> 8;
  const int j0 = tile * 64;
  __shared__ float t[64][65];           // +1 pad: conflict-free both phases
  const int lj = threadIdx.x & 63;      // lane = j (read) / cc (write)
  const int r0 = threadIdx.x >> 6;      // 0..3
  const float* fb = feats + (size_t)b * (CIN * NN);
#pragma unroll
  for (int cc = r0; cc < 64; cc += 4)
    t[cc][lj] = fb[(size_t)cc * NN + j0 + lj];        // coalesced along j
  __syncthreads();
  float* ob = featsT + (size_t)b * (NN * CIN);
#pragma unroll
  for (int jr = r0; jr < 64; jr += 4)
    ob[(size_t)(j0 + jr) * 64 + lj] = t[lj][jr];      // coalesced along cc
}

// ---------------- Ball query: one wave per centroid, ordered append with early exit ----------------
extern "C" __global__ __launch_bounds__(256)
void ball_kernel(const float* __restrict__ xyz, const float* __restrict__ newxyz,
                 int* __restrict__ ballidx) {
  const int lwv = threadIdx.x >> 6, lane = threadIdx.x & 63;
  const int wid = blockIdx.x * 4 + lwv;  // centroid id, 0..4095
  const int b = wid >> 10;
  const float* base = xyz + (size_t)b * (NN * 3);
  const float* c = newxyz + (size_t)wid * 3;
  float cx = c[0], cy = c[1], cz = c[2];
  float c2 = __fadd_rn(__fadd_rn(__fmul_rn(cx, cx), __fmul_rn(cy, cy)), __fmul_rn(cz, cz));
  __shared__ int list[4][NS];
  int cnt = 0;
  for (int j0 = 0; j0 < NN; j0 += 64) {
    int j = j0 + lane;
    float xx = base[3 * j + 0], xy = base[3 * j + 1], xz = base[3 * j + 2];
    float x2 = __fadd_rn(__fadd_rn(__fmul_rn(xx, xx), __fmul_rn(xy, xy)), __fmul_rn(xz, xz));
    float dt = __fadd_rn(__fadd_rn(__fmul_rn(cx, xx), __fmul_rn(cy, xy)), __fmul_rn(cz, xz));
    float d2 = __fsub_rn(__fadd_rn(c2, x2), __fmul_rn(2.0f, dt));  // (c2+x2) - 2*dot
    bool in = d2 < 0.25f;
    unsigned long long msk = __ballot(in);
    if (in) {
      int pos = cnt + (int)__popcll(msk & ((1ull << lane) - 1ull));
      if (pos < NS) list[lwv][pos] = j;
    }
    cnt += (int)__popcll(msk);
    if (cnt >= NS) break;
  }
  if (lane < NS) {
    int v;
    if (cnt == 0) v = 0;
    else v = (lane < cnt) ? list[lwv][lane] : list[lwv][0];
    ballidx[wid * NS + lane] = v;
  }
}

// ---------------- Gather + MLP(67->64->64->128) + max-pool, one block per (b,m) ----------------
extern "C" __global__ __launch_bounds__(256)
void mlp_kernel(const float* __restrict__ xyz, const float* __restrict__ feats,
                const float* __restrict__ featsT,   // point-major copy, or null (fallback)
                const float* __restrict__ newxyz, const int* __restrict__ ballidx,
                const float* __restrict__ W1, const float* __restrict__ b1,
                const float* __restrict__ W2, const float* __restrict__ b2,
                const float* __restrict__ W3, const float* __restrict__ b3,
                float* __restrict__ outf) {
  const int bm = blockIdx.x;
  const int b = bm >> 10, m = bm & 1023;
  const int tid = threadIdx.x;
  __align__(16) __shared__ float bufA[32 * 68];  // h0 (stride 68), then h2 (stride 64)
  __align__(16) __shared__ float bufB[32 * 64];  // h1, then partial max
  __shared__ int sidx[NS];
  if (tid < NS) sidx[tid] = ballidx[bm * NS + tid];
  const float* cb = newxyz + (size_t)bm * 3;
  float cx = cb[0], cy = cb[1], cz = cb[2];
  __syncthreads();
  // gather: 8 threads per sample
  {
    int s = tid >> 3, q = tid & 7;
    int j = sidx[s];
    float* row = bufA + s * 68;
    if (featsT) {
      // point-major: 8 consecutive channels per thread -> two float4 loads (256B/sample)
      const float* fr = featsT + ((size_t)b * NN + j) * 64 + (q << 3);
      float4 a0 = *(const float4*)fr;
      float4 a1 = *(const float4*)(fr + 4);
      float* rp = row + 3 + (q << 3);
      rp[0] = a0.x; rp[1] = a0.y; rp[2] = a0.z; rp[3] = a0.w;
      rp[4] = a1.x; rp[5] = a1.y; rp[6] = a1.z; rp[7] = a1.w;
    } else {
      const float* fb = feats + (size_t)b * (CIN * NN) + j;
#pragma unroll
      for (int u = 0; u < 8; ++u) {
        int cc = (q << 3) + u;
        row[3 + cc] = fb[(size_t)cc * NN];
      }
    }
    if (q == 0) {
      const float* p = xyz + ((size_t)b * NN + j) * 3;
      row[0] = __fsub_rn(p[0], cx);
      row[1] = __fsub_rn(p[1], cy);
      row[2] = __fsub_rn(p[2], cz);
      row[67] = 0.0f;
    }
  }
  __syncthreads();
  // layer 1: 67->64   (thread = (o, 8-sample group))
  {
    const int o = tid & 63, g = tid >> 6;
    float w[68];
    const float* wr = W1 + o * C0;
#pragma unroll
    for (int c = 0; c < C0; ++c) w[c] = wr[c];
    w[67] = 0.0f;
    float bias = b1[o];
    float acc[8];
#pragma unroll
    for (int k = 0; k < 8; ++k) acc[k] = bias;
#pragma unroll
    for (int c = 0; c < 68; c += 4) {
#pragma unroll
      for (int k = 0; k < 8; ++k) {
        float4 h = *(const float4*)(bufA + (g * 8 + k) * 68 + c);
        acc[k] = fmaf(w[c], h.x, acc[k]);
        acc[k] = fmaf(w[c + 1], h.y, acc[k]);
        acc[k] = fmaf(w[c + 2], h.z, acc[k]);
        acc[k] = fmaf(w[c + 3], h.w, acc[k]);
      }
    }
#pragma unroll
    for (int k = 0; k < 8; ++k) bufB[(g * 8 + k) * 64 + o] = fmaxf(acc[k], 0.0f);
  }
  __syncthreads();
  // layer 2: 64->64, h2 into bufA with stride 64
  {
    const int o = tid & 63, g = tid >> 6;
    float w[64];
    const float* wr = W2 + o * 64;
#pragma unroll
    for (int c = 0; c < 64; ++c) w[c] = wr[c];
    float bias = b2[o];
    float acc[8];
#pragma unroll
    for (int k = 0; k < 8; ++k) acc[k] = bias;
#pragma unroll
    for (int c = 0; c < 64; c += 4) {
#pragma unroll
      for (int k = 0; k < 8; ++k) {
        float4 h = *(const float4*)(bufB + (g * 8 + k) * 64 + c);
        acc[k] = fmaf(w[c], h.x, acc[k]);
        acc[k] = fmaf(w[c + 1], h.y, acc[k]);
        acc[k] = fmaf(w[c + 2], h.z, acc[k]);
        acc[k] = fmaf(w[c + 3], h.w, acc[k]);
      }
    }
#pragma unroll
    for (int k = 0; k < 8; ++k) bufA[(g * 8 + k) * 64 + o] = fmaxf(acc[k], 0.0f);
  }
  __syncthreads();
  // layer 3: 64->128 (thread = (o128, 16-sample group)), fused relu+max
  {
    const int o = tid & 127, g = tid >> 7;
    float w[64];
    const float* wr = W3 + o * 64;
#pragma unroll
    for (int c = 0; c < 64; ++c) w[c] = wr[c];
    float bias = b3[o];
    float acc[16];
#pragma unroll
    for (int k = 0; k < 16; ++k) acc[k] = bias;
#pragma unroll
    for (int kb = 0; kb < 16; kb += 8) {   // 8-sample sub-blocks to limit live registers
#pragma unroll
      for (int c = 0; c < 64; c += 4) {
#pragma unroll
        for (int k = 0; k < 8; ++k) {
          float4 h = *(const float4*)(bufA + (g * 16 + kb + k) * 64 + c);
          acc[kb + k] = fmaf(w[c], h.x, acc[kb + k]);
          acc[kb + k] = fmaf(w[c + 1], h.y, acc[kb + k]);
          acc[kb + k] = fmaf(w[c + 2], h.z, acc[kb + k]);
          acc[kb + k] = fmaf(w[c + 3], h.w, acc[kb + k]);
        }
      }
    }
    float mx = 0.0f;
#pragma unroll
    for (int k = 0; k < 16; ++k) mx = fmaxf(mx, fmaxf(acc[k], 0.0f));
    bufB[g * 128 + o] = mx;
  }
  __syncthreads();
  if (tid < 128) {
    float v = fmaxf(bufB[tid], bufB[128 + tid]);
    outf[((size_t)b * 128 + tid) * NPT + m] = v;
  }
}

extern "C" void kernel_launch(void* const* d_in, const int* in_sizes, int n_in,
                              void* d_out, int out_size, void* d_ws, size_t ws_size,
                              hipStream_t stream) {
  const float* xyz   = (const float*)d_in[0];
  const float* feats = (const float*)d_in[1];
  const float* W1 = (const float*)d_in[2];
  const float* b1 = (const float*)d_in[3];
  const float* W2 = (const float*)d_in[4];
  const float* b2 = (const float*)d_in[5];
  const float* W3 = (const float*)d_in[6];
  const float* b3 = (const float*)d_in[7];
  float* out = (float*)d_out;
  float* newxyz = out;                 // (4,1024,3)
  float* outf = out + NB * NPT * 3;    // (4,128,1024)
  int* ballidx = (int*)d_ws;           // 4096*32 ints at ws+0

  // featsT (16.78 MB) lives at ws+1MB if the workspace is big enough; else fall back
  const size_t ftOff = 1u << 20;
  const size_t ftBytes = (size_t)NB * NN * CIN * sizeof(float);
  float* featsT = (ws_size >= ftOff + ftBytes) ? (float*)((char*)d_ws + ftOff) : nullptr;

  if (featsT)
    hipLaunchKernelGGL(tr_kernel, dim3(NB * (NN / 64)), dim3(256), 0, stream, feats, featsT);
  hipLaunchKernelGGL(fps_kernel, dim3(NB), dim3(512), 0, stream, xyz, newxyz);
  hipLaunchKernelGGL(ball_kernel, dim3(NB * NPT / 4), dim3(256), 0, stream, xyz, newxyz, ballidx);
  hipLaunchKernelGGL(mlp_kernel, dim3(NB * NPT), dim3(256), 0, stream,
                     xyz, feats, featsT, newxyz, ballidx, W1, b1, W2, b2, W3, b3, outf);
}